// Round 4
// baseline (716.095 us; speedup 1.0000x reference)
//
#include <hip/hip_runtime.h>
#include <hip/hip_bf16.h>

// MSAAttentionBlock round 5: anti-spill hardening of the 339 µs structure
// (TILE=32, 1024 threads / 16 waves, 4 waves/SIMD, 1 block/CU by LDS).
// The current toolchain can't see the dynamic-LDS occupancy cap, aims for
// 8 waves/SIMD, clamps to 60 VGPR and spills 16 f32/thread (256 MB scratch
// traffic, 339->578 µs). Two redundant fixes:
//  (a) amdgpu_waves_per_eu(4,4): pin min AND max waves/EU -> regalloc gets
//      the full 128-VGPR budget (runtime occupancy is LDS-capped at 4/EU
//      anyway, so max=4 costs nothing).
//  (b) stage-1 split into 3+2 n-tile groups: peak live regs ~42 < 56, so
//      even a 60-VGPR-budget compiler cannot spill. Cost: one extra pass
//      over 16 ds_read_b128/wave, hidden under MFMA.

typedef __bf16 bf16;
typedef __bf16 bf16x8 __attribute__((ext_vector_type(8)));
typedef float f32x4 __attribute__((ext_vector_type(4)));

#define MFMA(a, b, c) __builtin_amdgcn_mfma_f32_16x16x32_bf16((a), (b), (c), 0, 0, 0)

#define THREADS 1024
#define TILE 32

constexpr int CIN = 256;

// packed-weight regions, in 8-element chunks (chunk = 16 B)
// layout per matrix: chunk lc = (nt*KT + kt)*64 + lane ; elems at lc*8
//   element j of chunk: B[k = kt*32 + (lane>>4)*8 + j][n = nt*16 + (lane&15)]
constexpr int CH_WQ = 0;                // 256x512  -> 16384 chunks, KT=8
constexpr int CH_WK = 16384;            // 256x512
constexpr int CH_WV = 32768;            // 256x256  -> 8192
constexpr int CH_W1 = 40960;            // 256x1024 -> 32768
constexpr int CH_WO = 73728;            // 1024x256 -> 32768, KT=32
constexpr int CH_WC = 106496;           // 256x256  -> 8192
constexpr int CH_TOT = 114688;          // * 16 B = 1.75 MB

// LDS layout (bf16 element offsets)
constexpr int L_XF  = 0;                // x A-frags:  2*8*64*8 = 8192
constexpr int L_AOF = 8192;             // ao A-frags: 8192
constexpr int L_C   = 16384;            // overlay region
constexpr int L_QS  = L_C;              // q plain [32][528]
constexpr int L_KS  = L_C + 16896;      // k plain [32][528]
constexpr int L_VS  = L_C + 33792;      // v plain [32][272]
constexpr int L_INTF = L_C;             // inter A-frags 2*32*64*8 = 32768 (aliases q/k/v)
constexpr int LDS_ELEMS = 16384 + 42496;   // 58880 bf16 = 117760 B -> 1 block/CU, 16 waves

__global__ void pack_w(const float* __restrict__ Wq, const float* __restrict__ Wk,
                       const float* __restrict__ Wv, const float* __restrict__ W1,
                       const float* __restrict__ Wo, const float* __restrict__ Wc,
                       bf16* __restrict__ ws) {
    int c = blockIdx.x * 256 + threadIdx.x;
    if (c >= CH_TOT) return;
    const float* W; int N, KT, lc;
    if (c < CH_WK)      { W = Wq; N = 512;  KT = 8;  lc = c - CH_WQ; }
    else if (c < CH_WV) { W = Wk; N = 512;  KT = 8;  lc = c - CH_WK; }
    else if (c < CH_W1) { W = Wv; N = 256;  KT = 8;  lc = c - CH_WV; }
    else if (c < CH_WO) { W = W1; N = 1024; KT = 8;  lc = c - CH_W1; }
    else if (c < CH_WC) { W = Wo; N = 256;  KT = 32; lc = c - CH_WO; }
    else                { W = Wc; N = 256;  KT = 8;  lc = c - CH_WC; }
    int lane = lc & 63, tmp = lc >> 6;
    int kt = tmp % KT, nt = tmp / KT;
    int k0 = kt * 32 + (lane >> 4) * 8;
    int n  = nt * 16 + (lane & 15);
    bf16x8 v;
    #pragma unroll
    for (int j = 0; j < 8; ++j) v[j] = (bf16)W[(size_t)(k0 + j) * N + n];
    *(bf16x8*)(ws + (size_t)c * 8) = v;
}

__device__ __forceinline__ bf16x8 lds_afrag(const bf16* smb, int baseoff, int KT,
                                            int mt, int kt, int lane) {
    return *(const bf16x8*)(smb + baseoff + (((mt * KT + kt) * 64) + lane) * 8);
}

// stage-1 QKV group: GN n-tiles starting at wave*5 + i0. Own kt-loop and
// epilogue so peak live registers stay ~42 regardless of compiler budget.
template<int GN>
__device__ __forceinline__ void qkv_group(bf16* smb, const bf16* __restrict__ ws,
                                          int wave, int lane, int col, int qd, int i0,
                                          const float* __restrict__ bq,
                                          const float* __restrict__ bk,
                                          const float* __restrict__ bv) {
    f32x4 acc[GN][2];
    #pragma unroll
    for (int i = 0; i < GN; ++i) {
        acc[i][0] = (f32x4){0.f, 0.f, 0.f, 0.f};
        acc[i][1] = (f32x4){0.f, 0.f, 0.f, 0.f};
    }
    const bf16* wbase[GN];
    #pragma unroll
    for (int i = 0; i < GN; ++i) {
        int g = wave * 5 + i0 + i;
        int ch;
        if (g < 32)      ch = CH_WQ + g * 512;          // nt*KT*64 = g*8*64
        else if (g < 64) ch = CH_WK + (g - 32) * 512;
        else             ch = CH_WV + (g - 64) * 512;
        wbase[i] = ws + ((size_t)ch + lane) * 8;
    }
    for (int kt = 0; kt < 8; ++kt) {
        bf16x8 a0 = lds_afrag(smb, L_XF, 8, 0, kt, lane);
        bf16x8 a1 = lds_afrag(smb, L_XF, 8, 1, kt, lane);
        #pragma unroll
        for (int i = 0; i < GN; ++i) {
            bf16x8 b = *(const bf16x8*)(wbase[i] + kt * 512);
            acc[i][0] = MFMA(a0, b, acc[i][0]);
            acc[i][1] = MFMA(a1, b, acc[i][1]);
        }
    }
    // epilogue: +bias, cvt bf16, scatter to plain q/k/v
    #pragma unroll
    for (int i = 0; i < GN; ++i) {
        int g = wave * 5 + i0 + i;
        int plane, stride, chan;
        float bias;
        if (g < 32)      { chan = g * 16 + col;        bias = bq[chan]; plane = L_QS; stride = 528; }
        else if (g < 64) { chan = (g - 32) * 16 + col; bias = bk[chan]; plane = L_KS; stride = 528; }
        else             { chan = (g - 64) * 16 + col; bias = bv[chan]; plane = L_VS; stride = 272; }
        #pragma unroll
        for (int mt = 0; mt < 2; ++mt)
            #pragma unroll
            for (int r = 0; r < 4; ++r) {
                int vox = mt * 16 + qd * 4 + r;
                smb[plane + vox * stride + chan] = (bf16)(acc[i][mt][r] + bias);
            }
    }
}

__global__ __launch_bounds__(THREADS)
__attribute__((amdgpu_waves_per_eu(4, 4)))
void msa_mfma(const float* __restrict__ x, const bf16* __restrict__ ws,
              const float* __restrict__ bq, const float* __restrict__ bk,
              const float* __restrict__ bv, const float* __restrict__ b1,
              const float* __restrict__ bo, const float* __restrict__ bc,
              const float* __restrict__ gamma, const float* __restrict__ beta,
              const float* __restrict__ mu, const float* __restrict__ var,
              float* __restrict__ out)
{
    extern __shared__ bf16 smb[];
    const int t = threadIdx.x;
    const int lane = t & 63;
    const int wave = t >> 6;                 // 0..15
    const int col = lane & 15;
    const int qd  = lane >> 4;
    const size_t base = (size_t)blockIdx.x * (TILE * CIN);

    // ---- stage 0: load x, convert to bf16, store in A-frag order ----
    // 1024 chunks, exactly one per thread
    {
        int c2 = t;
        int lc = c2 & 63, kt = (c2 >> 6) & 7, mt = c2 >> 9;
        int vox = mt * 16 + (lc & 15);
        int k0  = kt * 32 + (lc >> 4) * 8;
        const float* src = x + base + vox * 256 + k0;
        float4 f0 = *(const float4*)src;
        float4 f1 = *(const float4*)(src + 4);
        bf16x8 h;
        h[0] = (bf16)f0.x; h[1] = (bf16)f0.y; h[2] = (bf16)f0.z; h[3] = (bf16)f0.w;
        h[4] = (bf16)f1.x; h[5] = (bf16)f1.y; h[6] = (bf16)f1.z; h[7] = (bf16)f1.w;
        *(bf16x8*)&smb[L_XF + c2 * 8] = h;
    }
    __syncthreads();

    // ---- stage 1: QKV GEMM. 80 n-tiles (q:0-31, k:32-63, v:64-79), 5/wave,
    //      processed as a 3-group then a 2-group (register-pressure cap) ----
    qkv_group<3>(smb, ws, wave, lane, col, qd, 0, bq, bk, bv);
    qkv_group<2>(smb, ws, wave, lane, col, qd, 3, bq, bk, bv);
    __syncthreads();

    // ---- stage 2: attention, pair-split: thread = (vox, head, half) ----
    // 32 vox * 16 heads * 2 halves = 1024 threads, all active.
    // Each thread covers 8 of the 16 key-heads; shfl_xor(1) merges stats.
    // Score loop: outer d8, inner gg -> peak live floats ~24 (spill-proof).
    {
        const int half = t & 1;
        const int h   = (t >> 1) & 15;
        const int vox = t >> 5;
        const bf16* qp  = smb + L_QS + vox * 528 + h * 32;
        const bf16* kp0 = smb + L_KS + vox * 528 + (half * 8) * 32;
        float sc_[8];
        #pragma unroll
        for (int gg = 0; gg < 8; ++gg) sc_[gg] = 0.f;
        #pragma unroll
        for (int d8 = 0; d8 < 4; ++d8) {
            bf16x8 qv = *(const bf16x8*)(qp + d8 * 8);
            float qf[8];
            #pragma unroll
            for (int j = 0; j < 8; ++j) qf[j] = (float)qv[j];
            #pragma unroll
            for (int gg = 0; gg < 8; ++gg) {
                bf16x8 kv = *(const bf16x8*)(kp0 + gg * 32 + d8 * 8);  // broadcast across h
                #pragma unroll
                for (int j = 0; j < 8; ++j) sc_[gg] = fmaf((float)kv[j], qf[j], sc_[gg]);
            }
        }
        #pragma unroll
        for (int gg = 0; gg < 8; ++gg) sc_[gg] *= 0.17677669529663687f;  // 1/sqrt(32)
        float m = sc_[0];
        #pragma unroll
        for (int gg = 1; gg < 8; ++gg) m = fmaxf(m, sc_[gg]);
        m = fmaxf(m, __shfl_xor(m, 1));
        float sum = 0.f;
        #pragma unroll
        for (int gg = 0; gg < 8; ++gg) { sc_[gg] = __expf(sc_[gg] - m); sum += sc_[gg]; }
        sum += __shfl_xor(sum, 1);
        const float inv = 1.f / sum;
        float ao[16];
        #pragma unroll
        for (int j = 0; j < 16; ++j) ao[j] = 0.f;
        #pragma unroll
        for (int gg = 0; gg < 8; ++gg) {
            const float a = sc_[gg];
            const bf16* vp = smb + L_VS + vox * 272 + (half * 8 + gg) * 16;  // broadcast across h
            #pragma unroll
            for (int v8 = 0; v8 < 2; ++v8) {
                bf16x8 vv = *(const bf16x8*)(vp + v8 * 8);
                #pragma unroll
                for (int j = 0; j < 8; ++j)
                    ao[v8 * 8 + j] = fmaf(a, (float)vv[j], ao[v8 * 8 + j]);
            }
        }
        // merge the two halves' AV partials (both lanes end with the full sum)
        #pragma unroll
        for (int j = 0; j < 16; ++j) ao[j] += __shfl_xor(ao[j], 1);
        // write own dv-half in A-frag order for FFN1: chan c = h*16 + half*8 + j
        const int mt = vox >> 4, m_ = vox & 15, kt = h >> 1;
        const int quad = (h & 1) * 2 + half;
        bf16x8 o;
        #pragma unroll
        for (int j = 0; j < 8; ++j) o[j] = (bf16)(ao[half * 8 + j] * inv);
        *(bf16x8*)&smb[L_AOF + (((mt * 8 + kt) * 64) + quad * 16 + m_) * 8] = o;
    }
    __syncthreads();

    // ---- stage 3: FFN1 = relu(ao @ W1 + b1) -> inter A-frags. 64 n-tiles, 4/wave ----
    {
        f32x4 acc[4][2];
        #pragma unroll
        for (int i = 0; i < 4; ++i) {
            acc[i][0] = (f32x4){0.f, 0.f, 0.f, 0.f};
            acc[i][1] = (f32x4){0.f, 0.f, 0.f, 0.f};
        }
        const int n0 = wave * 4;
        for (int kt = 0; kt < 8; ++kt) {
            bf16x8 a0 = lds_afrag(smb, L_AOF, 8, 0, kt, lane);
            bf16x8 a1 = lds_afrag(smb, L_AOF, 8, 1, kt, lane);
            #pragma unroll
            for (int i = 0; i < 4; ++i) {
                bf16x8 b = *(const bf16x8*)(ws + ((size_t)(CH_W1 + ((n0 + i) * 8 + kt) * 64) + lane) * 8);
                acc[i][0] = MFMA(a0, b, acc[i][0]);
                acc[i][1] = MFMA(a1, b, acc[i][1]);
            }
        }
        // NOTE: no extra barrier needed before writing L_INTF — all q/k/v reads
        // completed before the stage2->3 __syncthreads above, and stage-3 waves
        // write channel-disjoint L_INTF ranges.
        #pragma unroll
        for (int i = 0; i < 4; ++i) {
            int c = (n0 + i) * 16 + col;
            float bias = b1[c];
            int kt2 = c >> 5;
            int q2  = (c & 31) >> 3;
            int j2  = c & 7;
            #pragma unroll
            for (int mt = 0; mt < 2; ++mt)
                #pragma unroll
                for (int r = 0; r < 4; ++r) {
                    int m_ = qd * 4 + r;
                    float v = fmaxf(acc[i][mt][r] + bias, 0.f);
                    smb[L_INTF + (((mt * 32 + kt2) * 64) + q2 * 16 + m_) * 8 + j2] = (bf16)v;
                }
        }
    }
    __syncthreads();

    // ---- stage 4: FFN2 (inter @ Wo) + residual (x @ Wc) + batchnorm. 1 n-tile/wave ----
    {
        f32x4 accF[2], accW[2];
        accF[0] = (f32x4){0.f, 0.f, 0.f, 0.f};
        accF[1] = (f32x4){0.f, 0.f, 0.f, 0.f};
        accW[0] = (f32x4){0.f, 0.f, 0.f, 0.f};
        accW[1] = (f32x4){0.f, 0.f, 0.f, 0.f};
        const int n0 = wave;
        for (int kt = 0; kt < 32; ++kt) {
            bf16x8 a0 = lds_afrag(smb, L_INTF, 32, 0, kt, lane);
            bf16x8 a1 = lds_afrag(smb, L_INTF, 32, 1, kt, lane);
            bf16x8 b = *(const bf16x8*)(ws + ((size_t)(CH_WO + (n0 * 32 + kt) * 64) + lane) * 8);
            accF[0] = MFMA(a0, b, accF[0]);
            accF[1] = MFMA(a1, b, accF[1]);
        }
        for (int kt = 0; kt < 8; ++kt) {
            bf16x8 a0 = lds_afrag(smb, L_XF, 8, 0, kt, lane);
            bf16x8 a1 = lds_afrag(smb, L_XF, 8, 1, kt, lane);
            bf16x8 b = *(const bf16x8*)(ws + ((size_t)(CH_WC + (n0 * 8 + kt) * 64) + lane) * 8);
            accW[0] = MFMA(a0, b, accW[0]);
            accW[1] = MFMA(a1, b, accW[1]);
        }
        {
            int c = n0 * 16 + col;
            float bo_ = bo[c], bc_ = bc[c];
            float scl = gamma[c] * rsqrtf(var[c] + 1e-6f);
            float mu_ = mu[c], be_ = beta[c];
            #pragma unroll
            for (int mt = 0; mt < 2; ++mt)
                #pragma unroll
                for (int r = 0; r < 4; ++r) {
                    int vox = mt * 16 + qd * 4 + r;
                    float res = fmaxf(accW[mt][r] + bc_, 0.f);
                    float iv  = accF[mt][r] + bo_;
                    out[base + vox * 256 + c] = (res + iv - mu_) * scl + be_;
                }
        }
    }
}

extern "C" void kernel_launch(void* const* d_in, const int* in_sizes, int n_in,
                              void* d_out, int out_size, void* d_ws, size_t ws_size,
                              hipStream_t stream) {
    const float* x     = (const float*)d_in[0];
    const float* Wq    = (const float*)d_in[1];
    const float* bq    = (const float*)d_in[2];
    const float* Wk    = (const float*)d_in[3];
    const float* bk    = (const float*)d_in[4];
    const float* Wv    = (const float*)d_in[5];
    const float* bv    = (const float*)d_in[6];
    const float* W1    = (const float*)d_in[7];
    const float* b1    = (const float*)d_in[8];
    const float* Wo    = (const float*)d_in[9];
    const float* bo    = (const float*)d_in[10];
    const float* Wc    = (const float*)d_in[11];
    const float* bc    = (const float*)d_in[12];
    const float* gamma = (const float*)d_in[13];
    const float* beta  = (const float*)d_in[14];
    const float* mu    = (const float*)d_in[15];
    const float* var   = (const float*)d_in[16];
    float* out = (float*)d_out;
    bf16* ws = (bf16*)d_ws;

    pack_w<<<(CH_TOT + 255) / 256, 256, 0, stream>>>(Wq, Wk, Wv, W1, Wo, Wc, ws);

    const int n = in_sizes[0] / CIN;           // 131072 voxels
    const int blocks = n / TILE;               // 4096
    const size_t smem = LDS_ELEMS * sizeof(bf16);  // 117760 B
    hipFuncSetAttribute(reinterpret_cast<const void*>(msa_mfma),
                        hipFuncAttributeMaxDynamicSharedMemorySize, (int)smem);
    msa_mfma<<<blocks, THREADS, smem, stream>>>(x, ws, bq, bk, bv, b1, bo, bc,
                                                gamma, beta, mu, var, out);
}

// Round 5
// 585.894 us; speedup vs baseline: 1.2222x; 1.2222x over previous
//
#include <hip/hip_runtime.h>
#include <hip/hip_bf16.h>

// MSAAttentionBlock round 6: scratch-spill root cause found and fixed.
// Rounds 2-4 lost 240 µs to EXACTLY 64 B/thread of scratch (WRITE_SIZE
// 131072->393216 KB, constant across stage-1 restructures). The culprit is
// stage-2's ao[16] read as ao[half*8+j] with RUNTIME half: this toolchain
// demotes runtime-indexed private arrays to scratch (rule #20). Fix: split
// into statically-indexed ao_lo[8]/ao_hi[8], merge each via shfl_xor(1),
// select own half with 8 per-element cndmasks. Everything else unchanged
// from the 339 µs structure (TILE=32, 1024 thr / 16 waves, 4 waves/SIMD,
// 1 block/CU by LDS); stage-1 3+2 split + waves_per_eu(4,4) kept as
// low-cost protection against 64-VGPR-budget compilers.

typedef __bf16 bf16;
typedef __bf16 bf16x8 __attribute__((ext_vector_type(8)));
typedef float f32x4 __attribute__((ext_vector_type(4)));

#define MFMA(a, b, c) __builtin_amdgcn_mfma_f32_16x16x32_bf16((a), (b), (c), 0, 0, 0)

#define THREADS 1024
#define TILE 32

constexpr int CIN = 256;

// packed-weight regions, in 8-element chunks (chunk = 16 B)
// layout per matrix: chunk lc = (nt*KT + kt)*64 + lane ; elems at lc*8
//   element j of chunk: B[k = kt*32 + (lane>>4)*8 + j][n = nt*16 + (lane&15)]
constexpr int CH_WQ = 0;                // 256x512  -> 16384 chunks, KT=8
constexpr int CH_WK = 16384;            // 256x512
constexpr int CH_WV = 32768;            // 256x256  -> 8192
constexpr int CH_W1 = 40960;            // 256x1024 -> 32768
constexpr int CH_WO = 73728;            // 1024x256 -> 32768, KT=32
constexpr int CH_WC = 106496;           // 256x256  -> 8192
constexpr int CH_TOT = 114688;          // * 16 B = 1.75 MB

// LDS layout (bf16 element offsets)
constexpr int L_XF  = 0;                // x A-frags:  2*8*64*8 = 8192
constexpr int L_AOF = 8192;             // ao A-frags: 8192
constexpr int L_C   = 16384;            // overlay region
constexpr int L_QS  = L_C;              // q plain [32][528]
constexpr int L_KS  = L_C + 16896;      // k plain [32][528]
constexpr int L_VS  = L_C + 33792;      // v plain [32][272]
constexpr int L_INTF = L_C;             // inter A-frags 2*32*64*8 = 32768 (aliases q/k/v)
constexpr int LDS_ELEMS = 16384 + 42496;   // 58880 bf16 = 117760 B -> 1 block/CU, 16 waves

__global__ void pack_w(const float* __restrict__ Wq, const float* __restrict__ Wk,
                       const float* __restrict__ Wv, const float* __restrict__ W1,
                       const float* __restrict__ Wo, const float* __restrict__ Wc,
                       bf16* __restrict__ ws) {
    int c = blockIdx.x * 256 + threadIdx.x;
    if (c >= CH_TOT) return;
    const float* W; int N, KT, lc;
    if (c < CH_WK)      { W = Wq; N = 512;  KT = 8;  lc = c - CH_WQ; }
    else if (c < CH_WV) { W = Wk; N = 512;  KT = 8;  lc = c - CH_WK; }
    else if (c < CH_W1) { W = Wv; N = 256;  KT = 8;  lc = c - CH_WV; }
    else if (c < CH_WO) { W = W1; N = 1024; KT = 8;  lc = c - CH_W1; }
    else if (c < CH_WC) { W = Wo; N = 256;  KT = 32; lc = c - CH_WO; }
    else                { W = Wc; N = 256;  KT = 8;  lc = c - CH_WC; }
    int lane = lc & 63, tmp = lc >> 6;
    int kt = tmp % KT, nt = tmp / KT;
    int k0 = kt * 32 + (lane >> 4) * 8;
    int n  = nt * 16 + (lane & 15);
    bf16x8 v;
    #pragma unroll
    for (int j = 0; j < 8; ++j) v[j] = (bf16)W[(size_t)(k0 + j) * N + n];
    *(bf16x8*)(ws + (size_t)c * 8) = v;
}

__device__ __forceinline__ bf16x8 lds_afrag(const bf16* smb, int baseoff, int KT,
                                            int mt, int kt, int lane) {
    return *(const bf16x8*)(smb + baseoff + (((mt * KT + kt) * 64) + lane) * 8);
}

// stage-1 QKV group: GN n-tiles starting at wave*5 + i0. Own kt-loop and
// epilogue so peak live registers stay ~42 regardless of compiler budget.
template<int GN>
__device__ __forceinline__ void qkv_group(bf16* smb, const bf16* __restrict__ ws,
                                          int wave, int lane, int col, int qd, int i0,
                                          const float* __restrict__ bq,
                                          const float* __restrict__ bk,
                                          const float* __restrict__ bv) {
    f32x4 acc[GN][2];
    #pragma unroll
    for (int i = 0; i < GN; ++i) {
        acc[i][0] = (f32x4){0.f, 0.f, 0.f, 0.f};
        acc[i][1] = (f32x4){0.f, 0.f, 0.f, 0.f};
    }
    const bf16* wbase[GN];
    #pragma unroll
    for (int i = 0; i < GN; ++i) {
        int g = wave * 5 + i0 + i;
        int ch;
        if (g < 32)      ch = CH_WQ + g * 512;          // nt*KT*64 = g*8*64
        else if (g < 64) ch = CH_WK + (g - 32) * 512;
        else             ch = CH_WV + (g - 64) * 512;
        wbase[i] = ws + ((size_t)ch + lane) * 8;
    }
    for (int kt = 0; kt < 8; ++kt) {
        bf16x8 a0 = lds_afrag(smb, L_XF, 8, 0, kt, lane);
        bf16x8 a1 = lds_afrag(smb, L_XF, 8, 1, kt, lane);
        #pragma unroll
        for (int i = 0; i < GN; ++i) {
            bf16x8 b = *(const bf16x8*)(wbase[i] + kt * 512);
            acc[i][0] = MFMA(a0, b, acc[i][0]);
            acc[i][1] = MFMA(a1, b, acc[i][1]);
        }
    }
    // epilogue: +bias, cvt bf16, scatter to plain q/k/v
    #pragma unroll
    for (int i = 0; i < GN; ++i) {
        int g = wave * 5 + i0 + i;
        int plane, stride, chan;
        float bias;
        if (g < 32)      { chan = g * 16 + col;        bias = bq[chan]; plane = L_QS; stride = 528; }
        else if (g < 64) { chan = (g - 32) * 16 + col; bias = bk[chan]; plane = L_KS; stride = 528; }
        else             { chan = (g - 64) * 16 + col; bias = bv[chan]; plane = L_VS; stride = 272; }
        #pragma unroll
        for (int mt = 0; mt < 2; ++mt)
            #pragma unroll
            for (int r = 0; r < 4; ++r) {
                int vox = mt * 16 + qd * 4 + r;
                smb[plane + vox * stride + chan] = (bf16)(acc[i][mt][r] + bias);
            }
    }
}

__global__ __launch_bounds__(THREADS)
__attribute__((amdgpu_waves_per_eu(4, 4)))
void msa_mfma(const float* __restrict__ x, const bf16* __restrict__ ws,
              const float* __restrict__ bq, const float* __restrict__ bk,
              const float* __restrict__ bv, const float* __restrict__ b1,
              const float* __restrict__ bo, const float* __restrict__ bc,
              const float* __restrict__ gamma, const float* __restrict__ beta,
              const float* __restrict__ mu, const float* __restrict__ var,
              float* __restrict__ out)
{
    extern __shared__ bf16 smb[];
    const int t = threadIdx.x;
    const int lane = t & 63;
    const int wave = t >> 6;                 // 0..15
    const int col = lane & 15;
    const int qd  = lane >> 4;
    const size_t base = (size_t)blockIdx.x * (TILE * CIN);

    // ---- stage 0: load x, convert to bf16, store in A-frag order ----
    // 1024 chunks, exactly one per thread
    {
        int c2 = t;
        int lc = c2 & 63, kt = (c2 >> 6) & 7, mt = c2 >> 9;
        int vox = mt * 16 + (lc & 15);
        int k0  = kt * 32 + (lc >> 4) * 8;
        const float* src = x + base + vox * 256 + k0;
        float4 f0 = *(const float4*)src;
        float4 f1 = *(const float4*)(src + 4);
        bf16x8 h;
        h[0] = (bf16)f0.x; h[1] = (bf16)f0.y; h[2] = (bf16)f0.z; h[3] = (bf16)f0.w;
        h[4] = (bf16)f1.x; h[5] = (bf16)f1.y; h[6] = (bf16)f1.z; h[7] = (bf16)f1.w;
        *(bf16x8*)&smb[L_XF + c2 * 8] = h;
    }
    __syncthreads();

    // ---- stage 1: QKV GEMM. 80 n-tiles (q:0-31, k:32-63, v:64-79), 5/wave,
    //      processed as a 3-group then a 2-group (register-pressure cap) ----
    qkv_group<3>(smb, ws, wave, lane, col, qd, 0, bq, bk, bv);
    qkv_group<2>(smb, ws, wave, lane, col, qd, 3, bq, bk, bv);
    __syncthreads();

    // ---- stage 2: attention, pair-split: thread = (vox, head, half) ----
    // 32 vox * 16 heads * 2 halves = 1024 threads, all active.
    // Each thread covers 8 of the 16 key-heads; shfl_xor(1) merges stats.
    // ALL private arrays statically indexed (rule #20): ao split lo/hi.
    {
        const int half = t & 1;
        const int h   = (t >> 1) & 15;
        const int vox = t >> 5;
        const bf16* qp  = smb + L_QS + vox * 528 + h * 32;
        const bf16* kp0 = smb + L_KS + vox * 528 + (half * 8) * 32;
        float sc_[8];
        #pragma unroll
        for (int gg = 0; gg < 8; ++gg) sc_[gg] = 0.f;
        #pragma unroll
        for (int d8 = 0; d8 < 4; ++d8) {
            bf16x8 qv = *(const bf16x8*)(qp + d8 * 8);
            float qf[8];
            #pragma unroll
            for (int j = 0; j < 8; ++j) qf[j] = (float)qv[j];
            #pragma unroll
            for (int gg = 0; gg < 8; ++gg) {
                bf16x8 kv = *(const bf16x8*)(kp0 + gg * 32 + d8 * 8);  // broadcast across h
                #pragma unroll
                for (int j = 0; j < 8; ++j) sc_[gg] = fmaf((float)kv[j], qf[j], sc_[gg]);
            }
        }
        #pragma unroll
        for (int gg = 0; gg < 8; ++gg) sc_[gg] *= 0.17677669529663687f;  // 1/sqrt(32)
        float m = sc_[0];
        #pragma unroll
        for (int gg = 1; gg < 8; ++gg) m = fmaxf(m, sc_[gg]);
        m = fmaxf(m, __shfl_xor(m, 1));
        float sum = 0.f;
        #pragma unroll
        for (int gg = 0; gg < 8; ++gg) { sc_[gg] = __expf(sc_[gg] - m); sum += sc_[gg]; }
        sum += __shfl_xor(sum, 1);
        const float inv = 1.f / sum;
        // AV accumulation: two statically-indexed 8-float halves (dv 0-7, 8-15)
        float ao_lo[8], ao_hi[8];
        #pragma unroll
        for (int j = 0; j < 8; ++j) { ao_lo[j] = 0.f; ao_hi[j] = 0.f; }
        #pragma unroll
        for (int gg = 0; gg < 8; ++gg) {
            const float a = sc_[gg];
            const bf16* vp = smb + L_VS + vox * 272 + (half * 8 + gg) * 16;  // broadcast across h
            bf16x8 v0 = *(const bf16x8*)(vp);
            bf16x8 v1 = *(const bf16x8*)(vp + 8);
            #pragma unroll
            for (int j = 0; j < 8; ++j) {
                ao_lo[j] = fmaf(a, (float)v0[j], ao_lo[j]);
                ao_hi[j] = fmaf(a, (float)v1[j], ao_hi[j]);
            }
        }
        // merge the two halves' AV partials (both lanes end with full sums)
        #pragma unroll
        for (int j = 0; j < 8; ++j) {
            ao_lo[j] += __shfl_xor(ao_lo[j], 1);
            ao_hi[j] += __shfl_xor(ao_hi[j], 1);
        }
        // write own dv-half in A-frag order for FFN1: chan c = h*16 + half*8 + j
        const int mt = vox >> 4, m_ = vox & 15, kt = h >> 1;
        const int quad = (h & 1) * 2 + half;
        bf16x8 o;
        #pragma unroll
        for (int j = 0; j < 8; ++j) {
            float v = half ? ao_hi[j] : ao_lo[j];   // per-element cndmask, no indexing
            o[j] = (bf16)(v * inv);
        }
        *(bf16x8*)&smb[L_AOF + (((mt * 8 + kt) * 64) + quad * 16 + m_) * 8] = o;
    }
    __syncthreads();

    // ---- stage 3: FFN1 = relu(ao @ W1 + b1) -> inter A-frags. 64 n-tiles, 4/wave ----
    {
        f32x4 acc[4][2];
        #pragma unroll
        for (int i = 0; i < 4; ++i) {
            acc[i][0] = (f32x4){0.f, 0.f, 0.f, 0.f};
            acc[i][1] = (f32x4){0.f, 0.f, 0.f, 0.f};
        }
        const int n0 = wave * 4;
        for (int kt = 0; kt < 8; ++kt) {
            bf16x8 a0 = lds_afrag(smb, L_AOF, 8, 0, kt, lane);
            bf16x8 a1 = lds_afrag(smb, L_AOF, 8, 1, kt, lane);
            #pragma unroll
            for (int i = 0; i < 4; ++i) {
                bf16x8 b = *(const bf16x8*)(ws + ((size_t)(CH_W1 + ((n0 + i) * 8 + kt) * 64) + lane) * 8);
                acc[i][0] = MFMA(a0, b, acc[i][0]);
                acc[i][1] = MFMA(a1, b, acc[i][1]);
            }
        }
        // NOTE: no extra barrier needed before writing L_INTF — all q/k/v reads
        // completed before the stage2->3 __syncthreads above, and stage-3 waves
        // write channel-disjoint L_INTF ranges.
        #pragma unroll
        for (int i = 0; i < 4; ++i) {
            int c = (n0 + i) * 16 + col;
            float bias = b1[c];
            int kt2 = c >> 5;
            int q2  = (c & 31) >> 3;
            int j2  = c & 7;
            #pragma unroll
            for (int mt = 0; mt < 2; ++mt)
                #pragma unroll
                for (int r = 0; r < 4; ++r) {
                    int m_ = qd * 4 + r;
                    float v = fmaxf(acc[i][mt][r] + bias, 0.f);
                    smb[L_INTF + (((mt * 32 + kt2) * 64) + q2 * 16 + m_) * 8 + j2] = (bf16)v;
                }
        }
    }
    __syncthreads();

    // ---- stage 4: FFN2 (inter @ Wo) + residual (x @ Wc) + batchnorm. 1 n-tile/wave ----
    {
        f32x4 accF[2], accW[2];
        accF[0] = (f32x4){0.f, 0.f, 0.f, 0.f};
        accF[1] = (f32x4){0.f, 0.f, 0.f, 0.f};
        accW[0] = (f32x4){0.f, 0.f, 0.f, 0.f};
        accW[1] = (f32x4){0.f, 0.f, 0.f, 0.f};
        const int n0 = wave;
        for (int kt = 0; kt < 32; ++kt) {
            bf16x8 a0 = lds_afrag(smb, L_INTF, 32, 0, kt, lane);
            bf16x8 a1 = lds_afrag(smb, L_INTF, 32, 1, kt, lane);
            bf16x8 b = *(const bf16x8*)(ws + ((size_t)(CH_WO + (n0 * 32 + kt) * 64) + lane) * 8);
            accF[0] = MFMA(a0, b, accF[0]);
            accF[1] = MFMA(a1, b, accF[1]);
        }
        for (int kt = 0; kt < 8; ++kt) {
            bf16x8 a0 = lds_afrag(smb, L_XF, 8, 0, kt, lane);
            bf16x8 a1 = lds_afrag(smb, L_XF, 8, 1, kt, lane);
            bf16x8 b = *(const bf16x8*)(ws + ((size_t)(CH_WC + (n0 * 8 + kt) * 64) + lane) * 8);
            accW[0] = MFMA(a0, b, accW[0]);
            accW[1] = MFMA(a1, b, accW[1]);
        }
        {
            int c = n0 * 16 + col;
            float bo_ = bo[c], bc_ = bc[c];
            float scl = gamma[c] * rsqrtf(var[c] + 1e-6f);
            float mu_ = mu[c], be_ = beta[c];
            #pragma unroll
            for (int mt = 0; mt < 2; ++mt)
                #pragma unroll
                for (int r = 0; r < 4; ++r) {
                    int vox = mt * 16 + qd * 4 + r;
                    float res = fmaxf(accW[mt][r] + bc_, 0.f);
                    float iv  = accF[mt][r] + bo_;
                    out[base + vox * 256 + c] = (res + iv - mu_) * scl + be_;
                }
        }
    }
}

extern "C" void kernel_launch(void* const* d_in, const int* in_sizes, int n_in,
                              void* d_out, int out_size, void* d_ws, size_t ws_size,
                              hipStream_t stream) {
    const float* x     = (const float*)d_in[0];
    const float* Wq    = (const float*)d_in[1];
    const float* bq    = (const float*)d_in[2];
    const float* Wk    = (const float*)d_in[3];
    const float* bk    = (const float*)d_in[4];
    const float* Wv    = (const float*)d_in[5];
    const float* bv    = (const float*)d_in[6];
    const float* W1    = (const float*)d_in[7];
    const float* b1    = (const float*)d_in[8];
    const float* Wo    = (const float*)d_in[9];
    const float* bo    = (const float*)d_in[10];
    const float* Wc    = (const float*)d_in[11];
    const float* bc    = (const float*)d_in[12];
    const float* gamma = (const float*)d_in[13];
    const float* beta  = (const float*)d_in[14];
    const float* mu    = (const float*)d_in[15];
    const float* var   = (const float*)d_in[16];
    float* out = (float*)d_out;
    bf16* ws = (bf16*)d_ws;

    pack_w<<<(CH_TOT + 255) / 256, 256, 0, stream>>>(Wq, Wk, Wv, W1, Wo, Wc, ws);

    const int n = in_sizes[0] / CIN;           // 131072 voxels
    const int blocks = n / TILE;               // 4096
    const size_t smem = LDS_ELEMS * sizeof(bf16);  // 117760 B
    hipFuncSetAttribute(reinterpret_cast<const void*>(msa_mfma),
                        hipFuncAttributeMaxDynamicSharedMemorySize, (int)smem);
    msa_mfma<<<blocks, THREADS, smem, stream>>>(x, ws, bq, bk, bv, b1, bo, bc,
                                                gamma, beta, mu, var, out);
}